// Round 4
// baseline (166.509 us; speedup 1.0000x reference)
//
#include <hip/hip_runtime.h>
#include <math.h>

// Fused ConvTranspose2d(64->64,k4,s2,p1) + BN + softmax(C) + maxpool2x2 via bf16 MFMA.
//
// Parity classes (r,p) of (oh,ow) -> 4 independent GEMMs sharing m=(n,ph,pw);
// maxpool = register max across the 4 class results.
// R4: block = (4 pooled rows, n). wave w <-> pooled row ph0+w, M = 4 m-tiles of 16.
// Each 16B weight bfrag feeds 4 MFMAs (was 1) -> weight L2 traffic /4.
// Halo: 6 input rows serve 4 output rows. LDS 57KB -> 2 blocks/CU, 256-VGPR budget.

typedef __attribute__((ext_vector_type(8))) short short8;
typedef __attribute__((ext_vector_type(4))) float floatx4;

#define PITCH 72   // cin dim padded 64->72 ushorts: 144B col stride, 16B-aligned frags
#define COLS 66

__device__ ushort g_wfrag[4 * 8 * 4 * 64 * 8];  // [class][ks][nt][lane][j], 128 KB
__device__ float g_aff[128];  // A = gamma*rsqrt(var+eps); D = (bias-mean)*A+beta

__device__ __forceinline__ ushort f2bf(float f) {
  union { float f; unsigned u; } v; v.f = f;
  unsigned r = v.u + 0x7FFF + ((v.u >> 16) & 1);  // RNE
  return (ushort)(r >> 16);
}

__global__ __launch_bounds__(256) void prep_kernel(
    const float* __restrict__ w, const float* __restrict__ bias,
    const float* __restrict__ gamma, const float* __restrict__ beta,
    const float* __restrict__ mean, const float* __restrict__ var) {
  // one thread = one 16B fragment row: 8 scattered reads, 1 dwordx4 write
  int idx = blockIdx.x * 256 + threadIdx.x;  // 0..8191
  int lane = idx & 63;
  int nt   = (idx >> 6) & 3;
  int ks   = (idx >> 8) & 7;
  int c    = (idx >> 11) & 3;
  int r = c >> 1, p = c & 1;
  int cout = nt * 16 + (lane & 15);
  ushort u[8];
#pragma unroll
  for (int j = 0; j < 8; ++j) {
    int k   = ks * 32 + (lane >> 4) * 8 + j;
    int tap = k >> 6, cin = k & 63;
    int a = tap >> 1, b = tap & 1;
    int kh = r ? (a ? 2 : 0) : (a ? 3 : 1);
    int kw = p ? (b ? 2 : 0) : (b ? 3 : 1);
    u[j] = f2bf(w[(cin * 64 + cout) * 16 + kh * 4 + kw]);
  }
  int4 pk;
  pk.x = u[0] | (u[1] << 16); pk.y = u[2] | (u[3] << 16);
  pk.z = u[4] | (u[5] << 16); pk.w = u[6] | (u[7] << 16);
  *(int4*)&g_wfrag[idx * 8] = pk;
  if (blockIdx.x == 0 && threadIdx.x < 64) {
    int ch = threadIdx.x;
    float A = gamma[ch] * rsqrtf(var[ch] + 1e-5f);
    g_aff[ch] = A;
    g_aff[64 + ch] = (bias[ch] - mean[ch]) * A + beta[ch];
  }
}

__global__ __launch_bounds__(256, 2) void fused_kernel(const float* __restrict__ x,
                                                       float* __restrict__ out) {
  __shared__ ushort xs[6 * COLS * PITCH];  // 57024 B; reused as f32 red[2][64][66]

  const int tid  = threadIdx.x;
  const int ph0  = blockIdx.x * 4;  // first pooled row of this block
  const int n    = blockIdx.y;
  const int wave = tid >> 6;
  const int lane = tid & 63;
  const int b15  = lane & 15;
  const int q    = lane >> 4;

  // ---- stage halo rows ph0-1 .. ph0+4, 64 cin bf16, [row][col][cin] ----
  for (int e = tid; e < 6 * 16 * 32; e += 256) {
    int iw2 = e & 31;          // pair of iw
    int c4  = (e >> 5) & 15;   // group of 4 cins
    int row = e >> 9;          // 0..5
    int ih  = ph0 - 1 + row;
    float2 v0 = {0.f, 0.f}, v1 = v0, v2 = v0, v3 = v0;
    if (ih >= 0 && ih < 64) {
      const float* xp = x + ((n * 64 + c4 * 4) * 64 + ih) * 64 + iw2 * 2;
      v0 = *(const float2*)xp;         v1 = *(const float2*)(xp + 4096);
      v2 = *(const float2*)(xp + 8192); v3 = *(const float2*)(xp + 12288);
    }
    ushort4 pa, pb;
    pa.x = f2bf(v0.x); pa.y = f2bf(v1.x); pa.z = f2bf(v2.x); pa.w = f2bf(v3.x);
    pb.x = f2bf(v0.y); pb.y = f2bf(v1.y); pb.z = f2bf(v2.y); pb.w = f2bf(v3.y);
    *(ushort4*)&xs[(row * COLS + iw2 * 2 + 1) * PITCH + c4 * 4] = pa;
    *(ushort4*)&xs[(row * COLS + iw2 * 2 + 2) * PITCH + c4 * 4] = pb;
  }
  // zero-pad cols 0 and 65
  for (int e = tid; e < 6 * 2 * 16; e += 256) {
    int c4 = e & 15, side = (e >> 4) & 1, row = e >> 5;
    ushort4 z; z.x = z.y = z.z = z.w = 0;
    *(ushort4*)&xs[(row * COLS + (side ? 65 : 0)) * PITCH + c4 * 4] = z;
  }
  __syncthreads();

  float Ac[4], Dc[4];
#pragma unroll
  for (int nt = 0; nt < 4; ++nt) {
    Ac[nt] = g_aff[nt * 16 + b15];
    Dc[nt] = g_aff[64 + nt * 16 + b15];
  }

  floatx4 pooled[16];  // [mt][nt] over reg; softmax outputs > 0
#pragma unroll
  for (int i = 0; i < 16; ++i) pooled[i] = (floatx4){0.f, 0.f, 0.f, 0.f};

#pragma unroll
  for (int c = 0; c < 4; ++c) {
    const int r = c >> 1, p = c & 1;
    floatx4 acc[16];
#pragma unroll
    for (int i = 0; i < 16; ++i) acc[i] = (floatx4){0.f, 0.f, 0.f, 0.f};

#pragma unroll
    for (int ks = 0; ks < 8; ++ks) {
      const int tap = ks >> 1, a = tap >> 1, b = tap & 1;
      // wave's pooled row ph0+wave; halo row index = ih - (ph0-1)
      const int hrow = wave + (r ? (a ? 1 : 2) : (a ? 0 : 1));
      const int dx   = p ? (b ? 0 : 1) : (b ? -1 : 0);
      const int cin0 = (ks & 1) * 32 + q * 8;
      const ushort* xrow = &xs[(hrow * COLS + 1 + dx + b15) * PITCH + cin0];
      short8 af[4];
#pragma unroll
      for (int mt = 0; mt < 4; ++mt)
        af[mt] = *(const short8*)&xrow[mt * 16 * PITCH];
      const short8* wf = (const short8*)&g_wfrag[((c * 8 + ks) * 4 * 64 + lane) * 8];
#pragma unroll
      for (int nt = 0; nt < 4; ++nt) {
        short8 bf = wf[nt * 64];
#pragma unroll
        for (int mt = 0; mt < 4; ++mt)
          acc[mt * 4 + nt] =
              __builtin_amdgcn_mfma_f32_16x16x32_bf16(af[mt], bf, acc[mt * 4 + nt], 0, 0, 0);
      }
    }

    // BN + softmax (no max-subtraction: |logit| <~ 5 analytically, exp exact in f32)
#pragma unroll
    for (int mt = 0; mt < 4; ++mt) {
      float v[16];
      float sm[4] = {0.f, 0.f, 0.f, 0.f};
#pragma unroll
      for (int nt = 0; nt < 4; ++nt)
#pragma unroll
        for (int reg = 0; reg < 4; ++reg) {
          float e = __expf(fmaf(acc[mt * 4 + nt][reg], Ac[nt], Dc[nt]));
          v[nt * 4 + reg] = e;
          sm[reg] += e;
        }
#pragma unroll
      for (int reg = 0; reg < 4; ++reg) {
        sm[reg] += __shfl_xor(sm[reg], 1, 64);
        sm[reg] += __shfl_xor(sm[reg], 2, 64);
        sm[reg] += __shfl_xor(sm[reg], 4, 64);
        sm[reg] += __shfl_xor(sm[reg], 8, 64);
        sm[reg] = 1.0f / sm[reg];
      }
#pragma unroll
      for (int nt = 0; nt < 4; ++nt)
#pragma unroll
        for (int reg = 0; reg < 4; ++reg)
          pooled[mt * 4 + nt][reg] =
              fmaxf(pooled[mt * 4 + nt][reg], v[nt * 4 + reg] * sm[reg]);
    }
  }

  // ---- output: 2 rows at a time transposed through LDS, coalesced stores ----
  __syncthreads();  // xs reads complete in all waves
  float* red = (float*)xs;  // [2][64 cout][66]
#pragma unroll
  for (int pp = 0; pp < 2; ++pp) {
    if ((wave >> 1) == pp) {
      int rl = wave & 1;
#pragma unroll
      for (int nt = 0; nt < 4; ++nt)
#pragma unroll
        for (int mt = 0; mt < 4; ++mt)
#pragma unroll
          for (int reg = 0; reg < 4; ++reg)
            red[(rl * 64 + nt * 16 + b15) * 66 + mt * 16 + q * 4 + reg] =
                pooled[mt * 4 + nt][reg];
    }
    __syncthreads();
    for (int e = tid; e < 4096; e += 256) {
      int pw2  = e & 31;
      int cout = (e >> 5) & 63;
      int rl   = e >> 11;
      float2 val = *(float2*)&red[(rl * 64 + cout) * 66 + pw2 * 2];
      *(float2*)&out[((n * 64 + cout) * 64 + (ph0 + pp * 2 + rl)) * 64 + pw2 * 2] = val;
    }
    __syncthreads();  // before next pass overwrites red
  }
}

extern "C" void kernel_launch(void* const* d_in, const int* in_sizes, int n_in,
                              void* d_out, int out_size, void* d_ws, size_t ws_size,
                              hipStream_t stream) {
  const float* x     = (const float*)d_in[0];
  const float* w     = (const float*)d_in[1];
  const float* bias  = (const float*)d_in[2];
  const float* gamma = (const float*)d_in[3];
  const float* beta  = (const float*)d_in[4];
  const float* mean  = (const float*)d_in[5];
  const float* var   = (const float*)d_in[6];
  float* out = (float*)d_out;

  prep_kernel<<<32, 256, 0, stream>>>(w, bias, gamma, beta, mean, var);
  dim3 grid(16, 32);  // (4-row groups, n)
  fused_kernel<<<grid, 256, 0, stream>>>(x, out);
}

// Round 5
// 127.278 us; speedup vs baseline: 1.3082x; 1.3082x over previous
//
#include <hip/hip_runtime.h>
#include <math.h>

// Fused ConvTranspose2d(64->64,k4,s2,p1) + BN + softmax(C) + maxpool2x2 via bf16 MFMA.
//
// Parity classes (r,p) of (oh,ow): 4 independent GEMMs sharing m=(n,ph,pw);
// maxpool = register max across class results. MFMA 16x16x32 bf16, K=256 (4 taps x 64 cin).
//
// R5: block = (2 pooled rows, n); wave = 1 pooled row x 32 pw (2 m-tiles) -> acc[8]+pooled[8]
//     (no R4 spill). Weights staged to LDS via global_load_lds w=16 (memory already in exact
//     fragment order), 16 KB buffer, 8 phases/block -> weight L2 traffic /8 vs R3.
//     x-halo XOR-swizzled (pitch 64, chunk^=col&7) -> conflict-free a-frag ds_read_b128.
//     LDS 33792 + 16384 = 50176 B -> 3 blocks/CU. Prep rewritten fully coalesced.

typedef __attribute__((ext_vector_type(8))) short short8;
typedef __attribute__((ext_vector_type(4))) float floatx4;

#define COLS 66

__device__ ushort g_wfrag[4 * 8 * 4 * 64 * 8];  // [class][ks][nt][lane][j], 128 KB
__device__ float g_aff[128];  // A = gamma*rsqrt(var+eps); D = (bias-mean)*A+beta

__device__ __forceinline__ ushort f2bf(float f) {
  union { float f; unsigned u; } v; v.f = f;
  unsigned r = v.u + 0x7FFF + ((v.u >> 16) & 1);  // RNE
  return (ushort)(r >> 16);
}

// prep: thread = (8-cin block, cout). Coalesced float4 reads (consecutive couts ->
// consecutive 64B rows); per (kh,kw) the 8 cins form one complete 16B j-row ->
// one dwordx4 store, consecutive couts -> contiguous 16B chunks.
__global__ __launch_bounds__(256) void prep_kernel(
    const float* __restrict__ w, const float* __restrict__ bias,
    const float* __restrict__ gamma, const float* __restrict__ beta,
    const float* __restrict__ mean, const float* __restrict__ var) {
  int t = blockIdx.x * 256 + threadIdx.x;  // 0..511
  int cin0 = (t >> 6) * 8;
  int cout = t & 63;
  int pack[16][4];  // per (kh*4+kw): 8 bf16 packed as 4 ints
#pragma unroll
  for (int e = 0; e < 16; ++e)
#pragma unroll
    for (int i = 0; i < 4; ++i) pack[e][i] = 0;

  for (int ci = 0; ci < 8; ++ci) {
    const float4* p = (const float4*)&w[((cin0 + ci) * 64 + cout) * 16];
    float4 f0 = p[0], f1 = p[1], f2 = p[2], f3 = p[3];
    float f[16] = {f0.x, f0.y, f0.z, f0.w, f1.x, f1.y, f1.z, f1.w,
                   f2.x, f2.y, f2.z, f2.w, f3.x, f3.y, f3.z, f3.w};
#pragma unroll
    for (int e = 0; e < 16; ++e)
      pack[e][ci >> 1] |= ((int)f2bf(f[e])) << ((ci & 1) * 16);
  }

  int ksq = cin0 >> 5;          // which 32-block of k within a tap
  int q   = (cin0 >> 3) & 3;    // quad within k-step
  int nt = cout >> 4, b15 = cout & 15;
#pragma unroll
  for (int kh = 0; kh < 4; ++kh)
#pragma unroll
    for (int kw = 0; kw < 4; ++kw) {
      int r = (kh & 1) ? 0 : 1;
      int pp = (kw & 1) ? 0 : 1;
      int c = r * 2 + pp;
      int tap = (kh >> 1) * 2 + (kw >> 1);
      int ks = tap * 2 + ksq;
      int4 pk = {pack[kh * 4 + kw][0], pack[kh * 4 + kw][1],
                 pack[kh * 4 + kw][2], pack[kh * 4 + kw][3]};
      *(int4*)&g_wfrag[((((c * 8 + ks) * 4 + nt) * 64) + q * 16 + b15) * 8] = pk;
    }

  if (t < 64) {
    float A = gamma[t] * rsqrtf(var[t] + 1e-5f);
    g_aff[t] = A;
    g_aff[64 + t] = (bias[t] - mean[t]) * A + beta[t];
  }
}

__global__ __launch_bounds__(256, 3) void fused_kernel(const float* __restrict__ x,
                                                       float* __restrict__ out) {
  __shared__ ushort xs[4 * COLS * 64];  // 33792 B halo (swizzled); reused as f32 red[2][64][66]
  __shared__ ushort wbuf[16 * 512];     // 16 KB weight stage (16 frags x 1KB)

  const int tid  = threadIdx.x;
  const int ph0  = blockIdx.x * 2;  // first pooled row
  const int n    = blockIdx.y;
  const int wave = tid >> 6;
  const int lane = tid & 63;
  const int b15  = lane & 15;
  const int q    = lane >> 4;
  const int wr   = wave >> 1;  // pooled row within block
  const int wc   = wave & 1;   // pw half (32 cols)

  // ---- stage x halo rows ph0-1..ph0+2, 64 cin bf16, swizzled [row][col][chunk^col&7] ----
  for (int e = tid; e < 4 * 16 * 32; e += 256) {
    int iw2 = e & 31;
    int c4  = (e >> 5) & 15;
    int row = e >> 9;  // 0..3
    int ih  = ph0 - 1 + row;
    float2 v0 = {0.f, 0.f}, v1 = v0, v2 = v0, v3 = v0;
    if (ih >= 0 && ih < 64) {
      const float* xp = x + ((n * 64 + c4 * 4) * 64 + ih) * 64 + iw2 * 2;
      v0 = *(const float2*)xp;          v1 = *(const float2*)(xp + 4096);
      v2 = *(const float2*)(xp + 8192); v3 = *(const float2*)(xp + 12288);
    }
    int chunk = c4 >> 1, half4 = (c4 & 1) * 4;
    {
      int col = iw2 * 2 + 1;
      ushort4 pk; pk.x = f2bf(v0.x); pk.y = f2bf(v1.x); pk.z = f2bf(v2.x); pk.w = f2bf(v3.x);
      *(ushort4*)&xs[(row * COLS + col) * 64 + ((chunk ^ (col & 7)) * 8) + half4] = pk;
    }
    {
      int col = iw2 * 2 + 2;
      ushort4 pk; pk.x = f2bf(v0.y); pk.y = f2bf(v1.y); pk.z = f2bf(v2.y); pk.w = f2bf(v3.y);
      *(ushort4*)&xs[(row * COLS + col) * 64 + ((chunk ^ (col & 7)) * 8) + half4] = pk;
    }
  }
  // zero-pad cols 0 and 65 (all chunks)
  for (int e = tid; e < 4 * 2 * 16; e += 256) {
    int c4 = e & 15, side = (e >> 4) & 1, row = e >> 5;
    int col = side ? 65 : 0;
    int chunk = c4 >> 1, half4 = (c4 & 1) * 4;
    ushort4 z; z.x = z.y = z.z = z.w = 0;
    *(ushort4*)&xs[(row * COLS + col) * 64 + ((chunk ^ (col & 7)) * 8) + half4] = z;
  }
  __syncthreads();

  float Ac[4], Dc[4];
#pragma unroll
  for (int nt = 0; nt < 4; ++nt) {
    Ac[nt] = g_aff[nt * 16 + b15];
    Dc[nt] = g_aff[64 + nt * 16 + b15];
  }

  floatx4 pooled[8];  // [mt*4+nt]; softmax outputs > 0
#pragma unroll
  for (int i = 0; i < 8; ++i) pooled[i] = (floatx4){0.f, 0.f, 0.f, 0.f};

  for (int c = 0; c < 4; ++c) {
    const int r = c >> 1, p = c & 1;
    floatx4 acc[8];
#pragma unroll
    for (int i = 0; i < 8; ++i) acc[i] = (floatx4){0.f, 0.f, 0.f, 0.f};

    for (int h = 0; h < 2; ++h) {
      // stage 16 frags (this class, ks h*4..h*4+3) -> wbuf; wave stages 4
#pragma unroll
      for (int ff = 0; ff < 4; ++ff) {
        int f = wave * 4 + ff;
        int ks_l = f >> 2, nt = f & 3;
        int gf = (c * 8 + h * 4 + ks_l) * 4 + nt;
        const ushort* gsrc = &g_wfrag[gf * 512 + lane * 8];
        __builtin_amdgcn_global_load_lds(
            (const __attribute__((address_space(1))) void*)gsrc,
            (__attribute__((address_space(3))) void*)&wbuf[f * 512], 16, 0, 0);
      }
      __syncthreads();  // compiler drains vmcnt before barrier -> staged data visible

#pragma unroll
      for (int ks_l = 0; ks_l < 4; ++ks_l) {
        const int ks = h * 4 + ks_l;
        const int tap = ks >> 1, a = tap >> 1, b = tap & 1;
        const int hrow = wr + (r ? (a ? 1 : 2) : (a ? 0 : 1));
        const int dx   = p ? (b ? 0 : 1) : (b ? -1 : 0);
        const int chunk = (ks & 1) * 4 + q;
        short8 af[2];
#pragma unroll
        for (int mt = 0; mt < 2; ++mt) {
          int col = wc * 32 + mt * 16 + b15 + dx + 1;
          af[mt] = *(const short8*)&xs[(hrow * COLS + col) * 64 + ((chunk ^ (col & 7)) * 8)];
        }
#pragma unroll
        for (int nt = 0; nt < 4; ++nt) {
          short8 bf = *(const short8*)&wbuf[(ks_l * 4 + nt) * 512 + lane * 8];
#pragma unroll
          for (int mt = 0; mt < 2; ++mt)
            acc[mt * 4 + nt] =
                __builtin_amdgcn_mfma_f32_16x16x32_bf16(af[mt], bf, acc[mt * 4 + nt], 0, 0, 0);
        }
      }
      __syncthreads();  // all waves done reading wbuf before next stage overwrites
    }

    // BN + softmax (no max-subtraction: |logit| <~ 5 analytically; exp exact in f32)
#pragma unroll
    for (int mt = 0; mt < 2; ++mt) {
      float v[16];
      float sm[4] = {0.f, 0.f, 0.f, 0.f};
#pragma unroll
      for (int nt = 0; nt < 4; ++nt)
#pragma unroll
        for (int reg = 0; reg < 4; ++reg) {
          float e = __expf(fmaf(acc[mt * 4 + nt][reg], Ac[nt], Dc[nt]));
          v[nt * 4 + reg] = e;
          sm[reg] += e;
        }
#pragma unroll
      for (int reg = 0; reg < 4; ++reg) {
        sm[reg] += __shfl_xor(sm[reg], 1, 64);
        sm[reg] += __shfl_xor(sm[reg], 2, 64);
        sm[reg] += __shfl_xor(sm[reg], 4, 64);
        sm[reg] += __shfl_xor(sm[reg], 8, 64);
        sm[reg] = 1.0f / sm[reg];
      }
#pragma unroll
      for (int nt = 0; nt < 4; ++nt)
#pragma unroll
        for (int reg = 0; reg < 4; ++reg)
          pooled[mt * 4 + nt][reg] =
              fmaxf(pooled[mt * 4 + nt][reg], v[nt * 4 + reg] * sm[reg]);
    }
  }

  // ---- output: transpose pooled through LDS (overlaid on halo), coalesced stores ----
  float* red = (float*)xs;  // [2 rows][64 cout][66]
#pragma unroll
  for (int mt = 0; mt < 2; ++mt)
#pragma unroll
    for (int nt = 0; nt < 4; ++nt)
#pragma unroll
      for (int reg = 0; reg < 4; ++reg)
        red[(wr * 64 + nt * 16 + b15) * 66 + wc * 32 + mt * 16 + q * 4 + reg] =
            pooled[mt * 4 + nt][reg];
  __syncthreads();
  for (int e = tid; e < 4096; e += 256) {
    int pw2  = e & 31;
    int cout = (e >> 5) & 63;
    int rl   = e >> 11;
    float2 val = *(float2*)&red[(rl * 64 + cout) * 66 + pw2 * 2];
    *(float2*)&out[((n * 64 + cout) * 64 + (ph0 + rl)) * 64 + pw2 * 2] = val;
  }
}

extern "C" void kernel_launch(void* const* d_in, const int* in_sizes, int n_in,
                              void* d_out, int out_size, void* d_ws, size_t ws_size,
                              hipStream_t stream) {
  const float* x     = (const float*)d_in[0];
  const float* w     = (const float*)d_in[1];
  const float* bias  = (const float*)d_in[2];
  const float* gamma = (const float*)d_in[3];
  const float* beta  = (const float*)d_in[4];
  const float* mean  = (const float*)d_in[5];
  const float* var   = (const float*)d_in[6];
  float* out = (float*)d_out;

  prep_kernel<<<2, 256, 0, stream>>>(w, bias, gamma, beta, mean, var);
  dim3 grid(32, 32);  // (2-row groups, n)
  fused_kernel<<<grid, 256, 0, stream>>>(x, out);
}

// Round 6
// 122.125 us; speedup vs baseline: 1.3634x; 1.0422x over previous
//
#include <hip/hip_runtime.h>
#include <math.h>

// Fused ConvTranspose2d(64->64,k4,s2,p1) + BN + softmax(C) + maxpool2x2 via bf16 MFMA.
//
// Parity classes (r,p) of (oh,ow): 4 independent GEMMs sharing m=(n,ph,pw);
// maxpool = register max across class results. MFMA 16x16x32 bf16, K=256 (4 taps x 64 cin).
//
// R6: bfrags read DIRECTLY global->VGPR (no LDS wbuf, no staging barriers) --
//     128 KB weight tensor is L2-resident and shared by every block. K-loop is
//     barrier-free -> compiler software-pipelines the 4 coalesced dwordx4 loads
//     per ks across MFMAs. LDS = halo only (33792 B) -> 4 blocks/CU.
//     Prep widened to 8 blocks (2048 threads, 2 cins each).

typedef __attribute__((ext_vector_type(8))) short short8;
typedef __attribute__((ext_vector_type(4))) float floatx4;

#define COLS 66

__device__ ushort g_wfrag[4 * 8 * 4 * 64 * 8];  // [class][ks][nt][lane][j], 128 KB
__device__ float g_aff[128];  // A = gamma*rsqrt(var+eps); D = (bias-mean)*A+beta

__device__ __forceinline__ ushort f2bf(float f) {
  union { float f; unsigned u; } v; v.f = f;
  unsigned r = v.u + 0x7FFF + ((v.u >> 16) & 1);  // RNE
  return (ushort)(r >> 16);
}

// prep: thread = (cin pair, cout). Reads two 64B rows (consecutive couts ->
// consecutive rows, coalesced). Each (kh,kw) gives one packed u32 (2 cins) ->
// dword store; consecutive couts -> 16B-strided (fine, L2 absorbs).
__global__ __launch_bounds__(256) void prep_kernel(
    const float* __restrict__ w, const float* __restrict__ bias,
    const float* __restrict__ gamma, const float* __restrict__ beta,
    const float* __restrict__ mean, const float* __restrict__ var) {
  int t = blockIdx.x * 256 + threadIdx.x;  // 0..2047
  int cin0 = (t >> 6) * 2;                 // even cin
  int cout = t & 63;
  int nt = cout >> 4, b15 = cout & 15;
  int q = (cin0 & 31) >> 3;                // quad within k-step
  int j = cin0 & 7;                        // j within quad (even)
  int ksq = cin0 >> 5;                     // which 32-block within tap

  const float4* p0 = (const float4*)&w[(cin0 * 64 + cout) * 16];
  const float4* p1 = (const float4*)&w[((cin0 + 1) * 64 + cout) * 16];
  float a[16], b[16];
  {
    float4 f0 = p0[0], f1 = p0[1], f2 = p0[2], f3 = p0[3];
    a[0]=f0.x; a[1]=f0.y; a[2]=f0.z; a[3]=f0.w; a[4]=f1.x; a[5]=f1.y; a[6]=f1.z; a[7]=f1.w;
    a[8]=f2.x; a[9]=f2.y; a[10]=f2.z; a[11]=f2.w; a[12]=f3.x; a[13]=f3.y; a[14]=f3.z; a[15]=f3.w;
    float4 g0 = p1[0], g1 = p1[1], g2 = p1[2], g3 = p1[3];
    b[0]=g0.x; b[1]=g0.y; b[2]=g0.z; b[3]=g0.w; b[4]=g1.x; b[5]=g1.y; b[6]=g1.z; b[7]=g1.w;
    b[8]=g2.x; b[9]=g2.y; b[10]=g2.z; b[11]=g2.w; b[12]=g3.x; b[13]=g3.y; b[14]=g3.z; b[15]=g3.w;
  }
#pragma unroll
  for (int kh = 0; kh < 4; ++kh)
#pragma unroll
    for (int kw = 0; kw < 4; ++kw) {
      int r = (kh & 1) ? 0 : 1;
      int pp = (kw & 1) ? 0 : 1;
      int c = r * 2 + pp;
      int tap = (kh >> 1) * 2 + (kw >> 1);
      int ks = tap * 2 + ksq;
      unsigned u = (unsigned)f2bf(a[kh * 4 + kw]) | ((unsigned)f2bf(b[kh * 4 + kw]) << 16);
      *(unsigned*)&g_wfrag[(((c * 8 + ks) * 4 + nt) * 64 + q * 16 + b15) * 8 + j] = u;
    }

  if (t < 64) {
    float A = gamma[t] * rsqrtf(var[t] + 1e-5f);
    g_aff[t] = A;
    g_aff[64 + t] = (bias[t] - mean[t]) * A + beta[t];
  }
}

__global__ __launch_bounds__(256, 4) void fused_kernel(const float* __restrict__ x,
                                                       float* __restrict__ out) {
  __shared__ ushort xs[4 * COLS * 64];  // 33792 B halo (swizzled); reused as f32 red[2][64][66]

  const int tid  = threadIdx.x;
  const int ph0  = blockIdx.x * 2;  // first pooled row
  const int n    = blockIdx.y;
  const int wave = tid >> 6;
  const int lane = tid & 63;
  const int b15  = lane & 15;
  const int q    = lane >> 4;
  const int wr   = wave >> 1;  // pooled row within block
  const int wc   = wave & 1;   // pw half (32 cols)

  // ---- stage x halo rows ph0-1..ph0+2, 64 cin bf16, swizzled [row][col][chunk^col&7] ----
  for (int e = tid; e < 4 * 16 * 32; e += 256) {
    int iw2 = e & 31;
    int c4  = (e >> 5) & 15;
    int row = e >> 9;  // 0..3
    int ih  = ph0 - 1 + row;
    float2 v0 = {0.f, 0.f}, v1 = v0, v2 = v0, v3 = v0;
    if (ih >= 0 && ih < 64) {
      const float* xp = x + ((n * 64 + c4 * 4) * 64 + ih) * 64 + iw2 * 2;
      v0 = *(const float2*)xp;          v1 = *(const float2*)(xp + 4096);
      v2 = *(const float2*)(xp + 8192); v3 = *(const float2*)(xp + 12288);
    }
    int chunk = c4 >> 1, half4 = (c4 & 1) * 4;
    {
      int col = iw2 * 2 + 1;
      ushort4 pk; pk.x = f2bf(v0.x); pk.y = f2bf(v1.x); pk.z = f2bf(v2.x); pk.w = f2bf(v3.x);
      *(ushort4*)&xs[(row * COLS + col) * 64 + ((chunk ^ (col & 7)) * 8) + half4] = pk;
    }
    {
      int col = iw2 * 2 + 2;
      ushort4 pk; pk.x = f2bf(v0.y); pk.y = f2bf(v1.y); pk.z = f2bf(v2.y); pk.w = f2bf(v3.y);
      *(ushort4*)&xs[(row * COLS + col) * 64 + ((chunk ^ (col & 7)) * 8) + half4] = pk;
    }
  }
  // zero-pad cols 0 and 65 (all chunks)
  for (int e = tid; e < 4 * 2 * 16; e += 256) {
    int c4 = e & 15, side = (e >> 4) & 1, row = e >> 5;
    int col = side ? 65 : 0;
    int chunk = c4 >> 1, half4 = (c4 & 1) * 4;
    ushort4 z; z.x = z.y = z.z = z.w = 0;
    *(ushort4*)&xs[(row * COLS + col) * 64 + ((chunk ^ (col & 7)) * 8) + half4] = z;
  }
  __syncthreads();

  float Ac[4], Dc[4];
#pragma unroll
  for (int nt = 0; nt < 4; ++nt) {
    Ac[nt] = g_aff[nt * 16 + b15];
    Dc[nt] = g_aff[64 + nt * 16 + b15];
  }

  floatx4 pooled[8];  // [mt*4+nt]; softmax outputs > 0
#pragma unroll
  for (int i = 0; i < 8; ++i) pooled[i] = (floatx4){0.f, 0.f, 0.f, 0.f};

  for (int c = 0; c < 4; ++c) {
    const int r = c >> 1, p = c & 1;
    floatx4 acc[8];
#pragma unroll
    for (int i = 0; i < 8; ++i) acc[i] = (floatx4){0.f, 0.f, 0.f, 0.f};

#pragma unroll
    for (int ks = 0; ks < 8; ++ks) {
      const int tap = ks >> 1, a = tap >> 1, b = tap & 1;
      const int hrow = wr + (r ? (a ? 1 : 2) : (a ? 0 : 1));
      const int dx   = p ? (b ? 0 : 1) : (b ? -1 : 0);
      const int chunk = (ks & 1) * 4 + q;
      // bfrags straight from L2: coalesced lane*16B, barrier-free, pipelined
      const short8* wf = (const short8*)&g_wfrag[((c * 8 + ks) * 4) * 512];
      short8 bf[4];
#pragma unroll
      for (int nt = 0; nt < 4; ++nt) bf[nt] = wf[nt * 64 + lane];
      short8 af[2];
#pragma unroll
      for (int mt = 0; mt < 2; ++mt) {
        int col = wc * 32 + mt * 16 + b15 + dx + 1;
        af[mt] = *(const short8*)&xs[(hrow * COLS + col) * 64 + ((chunk ^ (col & 7)) * 8)];
      }
#pragma unroll
      for (int nt = 0; nt < 4; ++nt)
#pragma unroll
        for (int mt = 0; mt < 2; ++mt)
          acc[mt * 4 + nt] =
              __builtin_amdgcn_mfma_f32_16x16x32_bf16(af[mt], bf[nt], acc[mt * 4 + nt], 0, 0, 0);
    }

    // BN + softmax (no max-subtraction: |logit| <~ 5 analytically; exp exact in f32)
#pragma unroll
    for (int mt = 0; mt < 2; ++mt) {
      float v[16];
      float sm[4] = {0.f, 0.f, 0.f, 0.f};
#pragma unroll
      for (int nt = 0; nt < 4; ++nt)
#pragma unroll
        for (int reg = 0; reg < 4; ++reg) {
          float e = __expf(fmaf(acc[mt * 4 + nt][reg], Ac[nt], Dc[nt]));
          v[nt * 4 + reg] = e;
          sm[reg] += e;
        }
#pragma unroll
      for (int reg = 0; reg < 4; ++reg) {
        sm[reg] += __shfl_xor(sm[reg], 1, 64);
        sm[reg] += __shfl_xor(sm[reg], 2, 64);
        sm[reg] += __shfl_xor(sm[reg], 4, 64);
        sm[reg] += __shfl_xor(sm[reg], 8, 64);
        sm[reg] = 1.0f / sm[reg];
      }
#pragma unroll
      for (int nt = 0; nt < 4; ++nt)
#pragma unroll
        for (int reg = 0; reg < 4; ++reg)
          pooled[mt * 4 + nt][reg] =
              fmaxf(pooled[mt * 4 + nt][reg], v[nt * 4 + reg] * sm[reg]);
    }
  }

  // ---- output: transpose pooled through LDS (overlaid on halo), coalesced stores ----
  __syncthreads();  // halo reads complete in all waves
  float* red = (float*)xs;  // [2 rows][64 cout][66]
#pragma unroll
  for (int mt = 0; mt < 2; ++mt)
#pragma unroll
    for (int nt = 0; nt < 4; ++nt)
#pragma unroll
      for (int reg = 0; reg < 4; ++reg)
        red[(wr * 64 + nt * 16 + b15) * 66 + wc * 32 + mt * 16 + q * 4 + reg] =
            pooled[mt * 4 + nt][reg];
  __syncthreads();
  for (int e = tid; e < 4096; e += 256) {
    int pw2  = e & 31;
    int cout = (e >> 5) & 63;
    int rl   = e >> 11;
    float2 val = *(float2*)&red[(rl * 64 + cout) * 66 + pw2 * 2];
    *(float2*)&out[((n * 64 + cout) * 64 + (ph0 + rl)) * 64 + pw2 * 2] = val;
  }
}

extern "C" void kernel_launch(void* const* d_in, const int* in_sizes, int n_in,
                              void* d_out, int out_size, void* d_ws, size_t ws_size,
                              hipStream_t stream) {
  const float* x     = (const float*)d_in[0];
  const float* w     = (const float*)d_in[1];
  const float* bias  = (const float*)d_in[2];
  const float* gamma = (const float*)d_in[3];
  const float* beta  = (const float*)d_in[4];
  const float* mean  = (const float*)d_in[5];
  const float* var   = (const float*)d_in[6];
  float* out = (float*)d_out;

  prep_kernel<<<8, 256, 0, stream>>>(w, bias, gamma, beta, mean, var);
  dim3 grid(32, 32);  // (2-row groups, n)
  fused_kernel<<<grid, 256, 0, stream>>>(x, out);
}

// Round 7
// 120.790 us; speedup vs baseline: 1.3785x; 1.0111x over previous
//
#include <hip/hip_runtime.h>
#include <hip/hip_bf16.h>
#include <math.h>

// Fused ConvTranspose2d(64->64,k4,s2,p1) + BN + softmax(C) + maxpool2x2 via bf16 MFMA.
//
// Parity classes (r,p) of (oh,ow): 4 independent GEMMs sharing m=(n,ph,pw);
// maxpool = register max across class results. MFMA 16x16x32 bf16, K=256 (4 taps x 64 cin).
//
// R7: bfrag global->VGPR loads explicitly DOUBLE-BUFFERED (ping-pong bfA/bfB):
//     next ks's 4 loads issue before current ks's MFMAs -> s_waitcnt vmcnt(4)
//     instead of vmcnt(0); class-boundary prefetch hides ks=0 under the softmax.
//     BN scale folded into weights at prep (epilogue = exp(conv'+D)) to free regs.
//     VGPR budget <=128 (4 waves/SIMD, LDS 33792 -> 4 blocks/CU).

typedef __attribute__((ext_vector_type(8))) short short8;
typedef __attribute__((ext_vector_type(4))) float floatx4;

#define COLS 66

__device__ ushort g_wfrag[4 * 8 * 4 * 64 * 8];  // [class][ks][nt][lane][j], 128 KB
__device__ float g_aff[64];  // D = (bias-mean)*A+beta  (A folded into weights)

__device__ __forceinline__ ushort f2bf(float f) {
  union { float f; unsigned u; } v; v.f = f;
  unsigned r = v.u + 0x7FFF + ((v.u >> 16) & 1);  // RNE
  return (ushort)(r >> 16);
}

// prep: thread = (cin pair, cout). BN scale A[cout] folded into weights here.
__global__ __launch_bounds__(256) void prep_kernel(
    const float* __restrict__ w, const float* __restrict__ bias,
    const float* __restrict__ gamma, const float* __restrict__ beta,
    const float* __restrict__ mean, const float* __restrict__ var) {
  int t = blockIdx.x * 256 + threadIdx.x;  // 0..2047
  int cin0 = (t >> 6) * 2;                 // even cin
  int cout = t & 63;
  int nt = cout >> 4, b15 = cout & 15;
  int q = (cin0 & 31) >> 3;                // quad within k-step
  int j = cin0 & 7;                        // j within quad (even)
  int ksq = cin0 >> 5;                     // which 32-block within tap
  float A = gamma[cout] * rsqrtf(var[cout] + 1e-5f);

  const float4* p0 = (const float4*)&w[(cin0 * 64 + cout) * 16];
  const float4* p1 = (const float4*)&w[((cin0 + 1) * 64 + cout) * 16];
  float a[16], b[16];
  {
    float4 f0 = p0[0], f1 = p0[1], f2 = p0[2], f3 = p0[3];
    a[0]=f0.x; a[1]=f0.y; a[2]=f0.z; a[3]=f0.w; a[4]=f1.x; a[5]=f1.y; a[6]=f1.z; a[7]=f1.w;
    a[8]=f2.x; a[9]=f2.y; a[10]=f2.z; a[11]=f2.w; a[12]=f3.x; a[13]=f3.y; a[14]=f3.z; a[15]=f3.w;
    float4 g0 = p1[0], g1 = p1[1], g2 = p1[2], g3 = p1[3];
    b[0]=g0.x; b[1]=g0.y; b[2]=g0.z; b[3]=g0.w; b[4]=g1.x; b[5]=g1.y; b[6]=g1.z; b[7]=g1.w;
    b[8]=g2.x; b[9]=g2.y; b[10]=g2.z; b[11]=g2.w; b[12]=g3.x; b[13]=g3.y; b[14]=g3.z; b[15]=g3.w;
  }
#pragma unroll
  for (int kh = 0; kh < 4; ++kh)
#pragma unroll
    for (int kw = 0; kw < 4; ++kw) {
      int r = (kh & 1) ? 0 : 1;
      int pp = (kw & 1) ? 0 : 1;
      int c = r * 2 + pp;
      int tap = (kh >> 1) * 2 + (kw >> 1);
      int ks = tap * 2 + ksq;
      unsigned u = (unsigned)f2bf(a[kh * 4 + kw] * A) |
                   ((unsigned)f2bf(b[kh * 4 + kw] * A) << 16);
      *(unsigned*)&g_wfrag[(((c * 8 + ks) * 4 + nt) * 64 + q * 16 + b15) * 8 + j] = u;
    }

  if (t < 64) {
    float Ai = gamma[t] * rsqrtf(var[t] + 1e-5f);
    g_aff[t] = (bias[t] - mean[t]) * Ai + beta[t];
  }
}

__global__ __launch_bounds__(256, 4) void fused_kernel(const float* __restrict__ x,
                                                       float* __restrict__ out) {
  __shared__ ushort xs[4 * COLS * 64];  // 33792 B halo (swizzled); reused as f32 red[2][64][66]

  const int tid  = threadIdx.x;
  const int ph0  = blockIdx.x * 2;  // first pooled row
  const int n    = blockIdx.y;
  const int wave = tid >> 6;
  const int lane = tid & 63;
  const int b15  = lane & 15;
  const int q    = lane >> 4;
  const int wr   = wave >> 1;  // pooled row within block
  const int wc   = wave & 1;   // pw half (32 cols)

  // ---- stage x halo rows ph0-1..ph0+2, 64 cin bf16, swizzled [row][col][chunk^col&7] ----
  for (int e = tid; e < 4 * 16 * 16; e += 256) {
    int iw4 = e & 15;          // group of 4 iw
    int c4  = (e >> 4) & 15;   // group of 4 cin
    int row = e >> 8;          // 0..3
    int ih  = ph0 - 1 + row;
    float4 v0 = {0.f, 0.f, 0.f, 0.f}, v1 = v0, v2 = v0, v3 = v0;
    if (ih >= 0 && ih < 64) {
      const float* xp = x + ((n * 64 + c4 * 4) * 64 + ih) * 64 + iw4 * 4;
      v0 = *(const float4*)xp;          v1 = *(const float4*)(xp + 4096);
      v2 = *(const float4*)(xp + 8192); v3 = *(const float4*)(xp + 12288);
    }
    int chunk = c4 >> 1, half4 = (c4 & 1) * 4;
    float cc[4][4] = {{v0.x, v1.x, v2.x, v3.x}, {v0.y, v1.y, v2.y, v3.y},
                      {v0.z, v1.z, v2.z, v3.z}, {v0.w, v1.w, v2.w, v3.w}};
#pragma unroll
    for (int ii = 0; ii < 4; ++ii) {
      int col = iw4 * 4 + ii + 1;
      __hip_bfloat162 lo = __float22bfloat162_rn({cc[ii][0], cc[ii][1]});
      __hip_bfloat162 hi = __float22bfloat162_rn({cc[ii][2], cc[ii][3]});
      ushort4 pk = {*(ushort*)&lo.x, *(ushort*)&lo.y, *(ushort*)&hi.x, *(ushort*)&hi.y};
      *(ushort4*)&xs[(row * COLS + col) * 64 + ((chunk ^ (col & 7)) * 8) + half4] = pk;
    }
  }
  // zero-pad cols 0 and 65 (all chunks)
  for (int e = tid; e < 4 * 2 * 16; e += 256) {
    int c4 = e & 15, side = (e >> 4) & 1, row = e >> 5;
    int col = side ? 65 : 0;
    int chunk = c4 >> 1, half4 = (c4 & 1) * 4;
    ushort4 z; z.x = z.y = z.z = z.w = 0;
    *(ushort4*)&xs[(row * COLS + col) * 64 + ((chunk ^ (col & 7)) * 8) + half4] = z;
  }
  __syncthreads();

  float Dc[4];
#pragma unroll
  for (int nt = 0; nt < 4; ++nt) Dc[nt] = g_aff[nt * 16 + b15];

  floatx4 pooled[8];  // [mt*4+nt]; softmax outputs > 0
#pragma unroll
  for (int i = 0; i < 8; ++i) pooled[i] = (floatx4){0.f, 0.f, 0.f, 0.f};

  // bfrag double buffers; A holds ks=0 of the current class at each class entry
  short8 bfA[4], bfB[4];
  {
    const short8* wf = (const short8*)g_wfrag;  // class 0, ks 0
#pragma unroll
    for (int nt = 0; nt < 4; ++nt) bfA[nt] = wf[nt * 64 + lane];
  }

  for (int c = 0; c < 4; ++c) {
    const int r = c >> 1, p = c & 1;
    floatx4 acc[8];
#pragma unroll
    for (int i = 0; i < 8; ++i) acc[i] = (floatx4){0.f, 0.f, 0.f, 0.f};

#pragma unroll
    for (int ks = 0; ks < 8; ++ks) {
      short8* cur = (ks & 1) ? bfB : bfA;
      short8* nxt = (ks & 1) ? bfA : bfB;
      // ---- prefetch next bfrags (next ks, or next class's ks=0) ----
      if (ks < 7) {
        const short8* wf = (const short8*)g_wfrag + (c * 8 + ks + 1) * 256;
#pragma unroll
        for (int nt = 0; nt < 4; ++nt) nxt[nt] = wf[nt * 64 + lane];
      } else if (c < 3) {
        const short8* wf = (const short8*)g_wfrag + (c + 1) * 8 * 256;
#pragma unroll
        for (int nt = 0; nt < 4; ++nt) nxt[nt] = wf[nt * 64 + lane];
      }
      // ---- a-frags from LDS ----
      const int a = ks >> 2, b = (ks >> 1) & 1;
      const int hrow = wr + (r ? (a ? 1 : 2) : (a ? 0 : 1));
      const int dx   = p ? (b ? 0 : 1) : (b ? -1 : 0);
      const int chunk = (ks & 1) * 4 + q;
      short8 af[2];
#pragma unroll
      for (int mt = 0; mt < 2; ++mt) {
        int col = wc * 32 + mt * 16 + b15 + dx + 1;
        af[mt] = *(const short8*)&xs[(hrow * COLS + col) * 64 + ((chunk ^ (col & 7)) * 8)];
      }
      // ---- MFMAs on current buffer (waitcnt leaves prefetch in flight) ----
#pragma unroll
      for (int nt = 0; nt < 4; ++nt)
#pragma unroll
        for (int mt = 0; mt < 2; ++mt)
          acc[mt * 4 + nt] =
              __builtin_amdgcn_mfma_f32_16x16x32_bf16(af[mt], cur[nt], acc[mt * 4 + nt], 0, 0, 0);
    }

    // BN-bias + softmax, exp in place (no max-subtraction: |logit| <~ 5; exp exact in f32)
#pragma unroll
    for (int mt = 0; mt < 2; ++mt) {
      float sm[4] = {0.f, 0.f, 0.f, 0.f};
#pragma unroll
      for (int nt = 0; nt < 4; ++nt)
#pragma unroll
        for (int reg = 0; reg < 4; ++reg) {
          float e = __expf(acc[mt * 4 + nt][reg] + Dc[nt]);
          acc[mt * 4 + nt][reg] = e;
          sm[reg] += e;
        }
#pragma unroll
      for (int reg = 0; reg < 4; ++reg) {
        sm[reg] += __shfl_xor(sm[reg], 1, 64);
        sm[reg] += __shfl_xor(sm[reg], 2, 64);
        sm[reg] += __shfl_xor(sm[reg], 4, 64);
        sm[reg] += __shfl_xor(sm[reg], 8, 64);
        sm[reg] = 1.0f / sm[reg];
      }
#pragma unroll
      for (int nt = 0; nt < 4; ++nt)
#pragma unroll
        for (int reg = 0; reg < 4; ++reg)
          pooled[mt * 4 + nt][reg] =
              fmaxf(pooled[mt * 4 + nt][reg], acc[mt * 4 + nt][reg] * sm[reg]);
    }
  }

  // ---- output: transpose pooled through LDS (overlaid on halo), coalesced stores ----
  __syncthreads();  // halo reads complete in all waves
  float* red = (float*)xs;  // [2 rows][64 cout][66]
#pragma unroll
  for (int mt = 0; mt < 2; ++mt)
#pragma unroll
    for (int nt = 0; nt < 4; ++nt)
#pragma unroll
      for (int reg = 0; reg < 4; ++reg)
        red[(wr * 64 + nt * 16 + b15) * 66 + wc * 32 + mt * 16 + q * 4 + reg] =
            pooled[mt * 4 + nt][reg];
  __syncthreads();
  for (int e = tid; e < 4096; e += 256) {
    int pw2  = e & 31;
    int cout = (e >> 5) & 63;
    int rl   = e >> 11;
    float2 val = *(float2*)&red[(rl * 64 + cout) * 66 + pw2 * 2];
    *(float2*)&out[((n * 64 + cout) * 64 + (ph0 + rl)) * 64 + pw2 * 2] = val;
  }
}

extern "C" void kernel_launch(void* const* d_in, const int* in_sizes, int n_in,
                              void* d_out, int out_size, void* d_ws, size_t ws_size,
                              hipStream_t stream) {
  const float* x     = (const float*)d_in[0];
  const float* w     = (const float*)d_in[1];
  const float* bias  = (const float*)d_in[2];
  const float* gamma = (const float*)d_in[3];
  const float* beta  = (const float*)d_in[4];
  const float* mean  = (const float*)d_in[5];
  const float* var   = (const float*)d_in[6];
  float* out = (float*)d_out;

  prep_kernel<<<8, 256, 0, stream>>>(w, bias, gamma, beta, mean, var);
  dim3 grid(32, 32);  // (2-row groups, n)
  fused_kernel<<<grid, 256, 0, stream>>>(x, out);
}